// Round 6
// baseline (901.341 us; speedup 1.0000x reference)
//
#include <hip/hip_runtime.h>
#include <hip/hip_bf16.h>

#define B_   16
#define N_   1024
#define KNN  20
#define NP   (B_ * N_)   // 16384

typedef short bf16x8 __attribute__((ext_vector_type(8)));
typedef float f32x4  __attribute__((ext_vector_type(4)));
typedef float f32x16 __attribute__((ext_vector_type(16)));

__device__ __forceinline__ unsigned short f2bf(float f) {
  unsigned u = __float_as_uint(f);
  u += 0x7fffu + ((u >> 16) & 1u);   // RNE
  return (unsigned short)(u >> 16);
}

// ---------------------------------------------------------------------------
// Row squared norms: sq[p] = sum_c X[p][c]^2  (fp32)
// ---------------------------------------------------------------------------
__global__ __launch_bounds__(256) void sqnorm_kernel(
    const float* __restrict__ X, int LD, int coff, int C, float* __restrict__ sq) {
  int p = blockIdx.x * 256 + threadIdx.x;
  const float* row = X + (size_t)p * LD + coff;
  float s = 0.f;
  if ((C & 3) == 0) {
    for (int c = 0; c < C; c += 4) {
      float4 vv = *(const float4*)(row + c);
      s = fmaf(vv.x, vv.x, s); s = fmaf(vv.y, vv.y, s);
      s = fmaf(vv.z, vv.z, s); s = fmaf(vv.w, vv.w, s);
    }
  } else {
    for (int c = 0; c < C; ++c) { float vv = row[c]; s = fmaf(vv, vv, s); }
  }
  sq[p] = s;
}

// ---------------------------------------------------------------------------
// Pairwise squared distances, Gram form (matches reference):
//   D[b,i,j] = (sq_i - 2*dot(x_i,x_j)) + sq_j
// fp32, fma-only inner loop. LDS tiles stored TRANSPOSED [c][row], stride 68.
// ---------------------------------------------------------------------------
__global__ __launch_bounds__(256) void pairdist_kernel(
    const float* __restrict__ X, int LD, int coff, int C,
    const float* __restrict__ sq, float* __restrict__ D) {
  __shared__ float Xi[16][68];
  __shared__ float Xj[16][68];
  int b  = blockIdx.z;
  int i0 = blockIdx.y * 64, j0 = blockIdx.x * 64;
  int t  = threadIdx.x;
  int tx = t & 15, ty = t >> 4;
  float acc[4][4] = {};
  for (int c0 = 0; c0 < C; c0 += 16) {
    int cc = min(16, C - c0);
    if (tx < cc) {
      for (int r = ty; r < 64; r += 16) {
        Xi[tx][r] = X[(size_t)(b * N_ + i0 + r) * LD + coff + c0 + tx];
        Xj[tx][r] = X[(size_t)(b * N_ + j0 + r) * LD + coff + c0 + tx];
      }
    }
    __syncthreads();
    for (int c = 0; c < cc; ++c) {
      float4 a4 = *(const float4*)&Xi[c][ty * 4];
      float4 b4 = *(const float4*)&Xj[c][tx * 4];
      float a[4] = {a4.x, a4.y, a4.z, a4.w};
      float bb[4] = {b4.x, b4.y, b4.z, b4.w};
#pragma unroll
      for (int p = 0; p < 4; ++p)
#pragma unroll
        for (int q = 0; q < 4; ++q)
          acc[p][q] = fmaf(a[p], bb[q], acc[p][q]);
    }
    __syncthreads();
  }
  float sqi[4], sqj[4];
#pragma unroll
  for (int p = 0; p < 4; ++p) sqi[p] = sq[b * N_ + i0 + ty * 4 + p];
#pragma unroll
  for (int q = 0; q < 4; ++q) sqj[q] = sq[b * N_ + j0 + tx * 4 + q];
#pragma unroll
  for (int p = 0; p < 4; ++p) {
    float4 st;
    st.x = (sqi[p] - 2.f * acc[p][0]) + sqj[0];
    st.y = (sqi[p] - 2.f * acc[p][1]) + sqj[1];
    st.z = (sqi[p] - 2.f * acc[p][2]) + sqj[2];
    st.w = (sqi[p] - 2.f * acc[p][3]) + sqj[3];
    *(float4*)&D[(size_t)(b * N_ + i0 + ty * 4 + p) * N_ + j0 + tx * 4] = st;
  }
}

// ---------------------------------------------------------------------------
// Top-K=20 smallest distances per point. One wave per point. Packed key
// (dist_bits << 10 | j): ties -> lowest j, matching jax.lax.top_k.
// ---------------------------------------------------------------------------
__global__ __launch_bounds__(256) void topk_kernel(
    const float* __restrict__ D, int* __restrict__ idx) {
  int w = threadIdx.x >> 6, lane = threadIdx.x & 63;
  int p = blockIdx.x * 4 + w;
  const float* row = D + (size_t)p * N_;
  unsigned long long key[16];
#pragma unroll
  for (int s = 0; s < 16; ++s) {
    float vv = row[lane + 64 * s];
    key[s] = ((unsigned long long)__float_as_uint(vv) << 10) | (unsigned)(lane + 64 * s);
  }
  int base = p & ~(N_ - 1);
  for (int k = 0; k < KNN; ++k) {
    unsigned long long m = key[0];
#pragma unroll
    for (int s = 1; s < 16; ++s) m = key[s] < m ? key[s] : m;
#pragma unroll
    for (int off = 32; off >= 1; off >>= 1) {
      unsigned long long o = __shfl_xor(m, off);
      if (o < m) m = o;
    }
    int j = (int)(m & 1023u);
    if (lane == 0) idx[p * KNN + k] = base + j;
    if ((j & 63) == lane) key[j >> 6] = ~0ull;
  }
}

// ---------------------------------------------------------------------------
// Per-point transform: u = x@(Wa_top - Wa_bot) + ba ; v = x@Wa_bot
// fp32 accumulate, bf16 out. X rows staged in LDS.
// ---------------------------------------------------------------------------
__global__ __launch_bounds__(256) void transform_kernel(
    const float* __restrict__ X, int LD, int coff, int Cin, int Cmid,
    const float* __restrict__ Wa, const float* __restrict__ ba,
    unsigned short* __restrict__ u, unsigned short* __restrict__ v) {
  __shared__ float xs[16 * 128];
  int w = threadIdx.x >> 6, lane = threadIdx.x & 63;
  int m  = blockIdx.y * 64 + lane;
  int p0 = blockIdx.x * 16;
  if ((Cin & 3) == 0) {
    for (int i = threadIdx.x; i < 16 * (Cin / 4); i += 256) {
      int pt = i / (Cin / 4), q = i - pt * (Cin / 4);
      *(float4*)&xs[pt * Cin + q * 4] =
          *(const float4*)&X[(size_t)(p0 + pt) * LD + coff + q * 4];
    }
  } else {
    for (int i = threadIdx.x; i < 16 * Cin; i += 256) {
      int pt = i / Cin, c = i - pt * Cin;
      xs[pt * Cin + c] = X[(size_t)(p0 + pt) * LD + coff + c];
    }
  }
  __syncthreads();
  const float* xw = xs + (w * 4) * Cin;
  float ua[4] = {0.f, 0.f, 0.f, 0.f}, va[4] = {0.f, 0.f, 0.f, 0.f};
  for (int c = 0; c < Cin; ++c) {
    float wt = Wa[(size_t)c * Cmid + m];
    float wb = Wa[(size_t)(Cin + c) * Cmid + m];
    float wd = wt - wb;
#pragma unroll
    for (int i = 0; i < 4; ++i) {
      float xv = xw[i * Cin + c];
      ua[i] = fmaf(xv, wd, ua[i]);
      va[i] = fmaf(xv, wb, va[i]);
    }
  }
  float bias = ba[m];
#pragma unroll
  for (int i = 0; i < 4; ++i) {
    u[(size_t)(p0 + w * 4 + i) * Cmid + m] = f2bf(ua[i] + bias);
    v[(size_t)(p0 + w * 4 + i) * Cmid + m] = f2bf(va[i]);
  }
}

// ---------------------------------------------------------------------------
// Transpose + convert Wb (Cmid x Cout, fp32) -> WbT (Cout x Cmid, bf16).
// ---------------------------------------------------------------------------
__global__ __launch_bounds__(256) void cvtw_kernel(
    const float* __restrict__ W, unsigned short* __restrict__ out, int Cmid, int Cout) {
  __shared__ unsigned short tile[32][33];
  int c0 = blockIdx.x * 32, co0 = blockIdx.y * 32;
  int tx = threadIdx.x & 31, ty = threadIdx.x >> 5;   // 32 x 8
  for (int r = ty; r < 32; r += 8)
    tile[r][tx] = f2bf(W[(size_t)(c0 + r) * Cout + co0 + tx]);
  __syncthreads();
  for (int r = ty; r < 32; r += 8)
    out[(size_t)(co0 + r) * Cmid + c0 + tx] = tile[tx][r];
}

// ---------------------------------------------------------------------------
// Edge MLP second GEMM + max-aggregate. v5: single-barrier software pipeline.
//   W_lds and qmax double-buffered; per col-group interval g does:
//     stage W(g+1) -> buf[(g+1)&1]   (global-load latency overlaps MFMA(g))
//     reduce(g-1)  <- qbuf[(g-1)&1]  (+ global store)
//     MFMA(g)      <- buf[g&1]
//     qwrite(g)    -> qbuf[g&1]
//   All cross-interval LDS dependencies are separated by exactly one barrier.
// Block: 320 threads (5 waves) = 160 edges = 8 points.
// ---------------------------------------------------------------------------
template<int Cmid, int Cout, int CG>
__global__ __launch_bounds__(320, 3) void edge_mlp_kernel(
    const unsigned short* __restrict__ u, const unsigned short* __restrict__ v,
    const int* __restrict__ idx,
    const unsigned short* __restrict__ wbt, const float* __restrict__ bb,
    float* __restrict__ xcat, int coff) {
  constexpr int AP = Cmid + 8;
  constexpr int T  = CG / 32;      // 32-col tiles per group
  constexpr int KC = Cmid / 16;    // k chunks of 16
  constexpr int G  = Cout / CG;    // col groups
  __shared__ __align__(16) unsigned short W_lds[2][CG * AP];
  __shared__ float qmax[2][40 * CG];
  int tid = threadIdx.x, w = tid >> 6, lane = tid & 63;
  int col = lane & 31, half = lane >> 5;

  int rg = blockIdx.x * 160 + w * 32 + col;
  int p  = rg / 20;
  int j  = idx[rg];
  const unsigned short* up = u + (size_t)p * Cmid + half * 8;
  const unsigned short* vp = v + (size_t)j * Cmid + half * 8;

  // A-fragments: relu(u_p + v_j) in bf16, register-resident for all groups.
  bf16x8 afr[KC];
#pragma unroll
  for (int c = 0; c < KC; ++c) {
    union { int4 i; __hip_bfloat162 h[4]; bf16x8 vec; } U, V, R;
    U.i = *(const int4*)(up + c * 16);
    V.i = *(const int4*)(vp + c * 16);
#pragma unroll
    for (int q = 0; q < 4; ++q) {
      float2 a = __bfloat1622float2(U.h[q]);
      float2 b = __bfloat1622float2(V.h[q]);
      R.h[q] = __float22bfloat162_rn({fmaxf(a.x + b.x, 0.f), fmaxf(a.y + b.y, 0.f)});
    }
    afr[c] = R.vec;
  }

  int brow = col * AP + half * 8;

  auto stage = [&](int g, unsigned short* dst) {
    for (int i = tid; i < CG * (Cmid / 8); i += 320) {
      int rr = i / (Cmid / 8), q = i - rr * (Cmid / 8);
      *(int4*)&dst[rr * AP + q * 8] =
          *(const int4*)&wbt[(size_t)(g * CG + rr) * Cmid + q * 8];
    }
  };

  stage(0, W_lds[0]);

  for (int g = 0; g <= G; ++g) {
    __syncthreads();
    if (g + 1 < G) stage(g + 1, W_lds[(g + 1) & 1]);
    if (g > 0) {
      const float* qb = qmax[(g - 1) & 1];
      for (int i = tid; i < 8 * CG; i += 320) {
        int pl = i / CG, c2 = i - pl * CG;
        float mm = qb[(pl * 5 + 0) * CG + c2];
#pragma unroll
        for (int qq = 1; qq < 5; ++qq) mm = fmaxf(mm, qb[(pl * 5 + qq) * CG + c2]);
        int pg = blockIdx.x * 8 + pl;
        xcat[(size_t)pg * 512 + coff + (g - 1) * CG + c2] = mm + bb[(g - 1) * CG + c2];
      }
    }
    if (g < G) {
      const unsigned short* wb = W_lds[g & 1];
      float* qb = qmax[g & 1];
      f32x16 acc[T] = {};
#pragma unroll
      for (int c = 0; c < KC; ++c) {
#pragma unroll
        for (int t = 0; t < T; ++t) {
          bf16x8 bf = *(const bf16x8*)&wb[brow + t * 32 * AP + c * 16];
          acc[t] = __builtin_amdgcn_mfma_f32_32x32x16_bf16(afr[c], bf, acc[t], 0, 0, 0);
        }
      }
#pragma unroll
      for (int t = 0; t < T; ++t) {
#pragma unroll
        for (int Q = 0; Q < 4; ++Q) {
          float m0 = fmaxf(fmaxf(acc[t][4 * Q], acc[t][4 * Q + 1]),
                           fmaxf(acc[t][4 * Q + 2], acc[t][4 * Q + 3]));
          qb[(w * 8 + 2 * Q + half) * CG + t * 32 + col] = m0;
        }
      }
    }
  }
}

// ---------------------------------------------------------------------------
// Global max pool, two-stage coalesced.
// ---------------------------------------------------------------------------
__global__ __launch_bounds__(256) void pool1_kernel(const float* __restrict__ xcat,
                                                    float* __restrict__ part) {
  int b = blockIdx.x, g = blockIdx.y, t = threadIdx.x;
  const float* base = xcat + ((size_t)b * N_ + g * 128) * 512 + t * 2;
  float mx = -__builtin_inff(), my = -__builtin_inff();
#pragma unroll 4
  for (int r = 0; r < 128; ++r) {
    float2 vv = *(const float2*)(base + (size_t)r * 512);
    mx = fmaxf(mx, vv.x);
    my = fmaxf(my, vv.y);
  }
  *(float2*)&part[((size_t)b * 8 + g) * 512 + t * 2] = make_float2(mx, my);
}

__global__ __launch_bounds__(256) void pool2_kernel(const float* __restrict__ part,
                                                    float* __restrict__ pooled) {
  int b = blockIdx.x, t = threadIdx.x;
  float2 m = *(const float2*)&part[(size_t)b * 8 * 512 + t * 2];
#pragma unroll
  for (int g = 1; g < 8; ++g) {
    float2 vv = *(const float2*)&part[((size_t)b * 8 + g) * 512 + t * 2];
    m.x = fmaxf(m.x, vv.x);
    m.y = fmaxf(m.y, vv.y);
  }
  *(float2*)&pooled[b * 512 + t * 2] = m;
}

__global__ __launch_bounds__(256) void lin1_kernel(const float* __restrict__ pooled,
                                                   const float* __restrict__ W,
                                                   const float* __restrict__ bias,
                                                   float* __restrict__ h) {
  int flat = blockIdx.x * 256 + threadIdx.x;
  int b = flat >> 10, m = flat & 1023;
  float s = 0.f;
  for (int c = 0; c < 512; ++c) s = fmaf(pooled[b * 512 + c], W[(size_t)c * 1024 + m], s);
  h[flat] = s + bias[m];
}

__global__ __launch_bounds__(256) void bn_kernel(const float* __restrict__ h,
                                                 const float* __restrict__ gamma,
                                                 const float* __restrict__ beta,
                                                 float* __restrict__ h2) {
  int m = blockIdx.x * 256 + threadIdx.x;
  float s = 0.f;
  for (int b = 0; b < 16; ++b) s += h[b * 1024 + m];
  float mu = s * (1.f / 16.f);
  float vv = 0.f;
  for (int b = 0; b < 16; ++b) { float d = h[b * 1024 + m] - mu; vv = fmaf(d, d, vv); }
  vv *= (1.f / 16.f);
  float rstd = rsqrtf(vv + 1e-5f);
  float g = gamma[m] * rstd, be = beta[m];
  for (int b = 0; b < 16; ++b) {
    float val = (h[b * 1024 + m] - mu) * g + be;
    h2[b * 1024 + m] = fmaxf(val, 0.f);
  }
}

__global__ __launch_bounds__(64) void lin2_kernel(const float* __restrict__ h2,
                                                  const float* __restrict__ W,
                                                  const float* __restrict__ bias,
                                                  float* __restrict__ out) {
  int b = blockIdx.x, lane = threadIdx.x;
  float logit = 0.f;
  if (lane < 40) {
    logit = bias[lane];
    for (int c = 0; c < 1024; ++c)
      logit = fmaf(h2[b * 1024 + c], W[(size_t)c * 40 + lane], logit);
  }
  float mv = (lane < 40) ? logit : -__builtin_inff();
#pragma unroll
  for (int off = 32; off >= 1; off >>= 1) mv = fmaxf(mv, __shfl_xor(mv, off));
  float e = (lane < 40) ? expf(logit - mv) : 0.f;
#pragma unroll
  for (int off = 32; off >= 1; off >>= 1) e += __shfl_xor(e, off);
  float lse = mv + logf(e);
  if (lane < 40) out[b * 40 + lane] = logit - lse;
}

// ---------------------------------------------------------------------------
extern "C" void kernel_launch(void* const* d_in, const int* in_sizes, int n_in,
                              void* d_out, int out_size, void* d_ws, size_t ws_size,
                              hipStream_t stream) {
  const float* pos    = (const float*)d_in[0];
  const float* W1a = (const float*)d_in[2];  const float* b1a = (const float*)d_in[3];
  const float* W1b = (const float*)d_in[4];  const float* b1b = (const float*)d_in[5];
  const float* W2a = (const float*)d_in[6];  const float* b2a = (const float*)d_in[7];
  const float* W2b = (const float*)d_in[8];  const float* b2b = (const float*)d_in[9];
  const float* W3a = (const float*)d_in[10]; const float* b3a = (const float*)d_in[11];
  const float* W3b = (const float*)d_in[12]; const float* b3b = (const float*)d_in[13];
  const float* W4a = (const float*)d_in[14]; const float* b4a = (const float*)d_in[15];
  const float* W4b = (const float*)d_in[16]; const float* b4b = (const float*)d_in[17];
  const float* lin1_w = (const float*)d_in[18]; const float* lin1_b = (const float*)d_in[19];
  const float* gamma  = (const float*)d_in[20]; const float* beta   = (const float*)d_in[21];
  const float* lin2_w = (const float*)d_in[22]; const float* lin2_b = (const float*)d_in[23];
  float* out = (float*)d_out;

  char* ws = (char*)d_ws;
  size_t off = 0;
  auto alloc = [&](size_t bytes) {
    void* p = ws + off; off += (bytes + 255) & ~(size_t)255; return p;
  };
  float* xcat = (float*)alloc((size_t)NP * 512 * 4);   // 32 MB
  float* D    = (float*)alloc((size_t)NP * N_ * 4);    // 64 MB (u/v alias inside)
  int*   idx  = (int*)alloc((size_t)NP * KNN * 4);
  float* sq   = (float*)alloc((size_t)NP * 4);
  unsigned short* wbt1 = (unsigned short*)alloc(64 * 64 * 2);
  unsigned short* wbt2 = (unsigned short*)alloc(64 * 64 * 2);
  unsigned short* wbt3 = (unsigned short*)alloc(128 * 128 * 2);
  unsigned short* wbt4 = (unsigned short*)alloc(256 * 256 * 2);
  float* h      = (float*)alloc(16 * 1024 * 4);
  float* h2     = (float*)alloc(16 * 1024 * 4);
  float* pooled = (float*)alloc(16 * 512 * 4);
  float* part   = (float*)alloc(16 * 8 * 512 * 4);
  unsigned short* u = (unsigned short*)D;              // bf16, aliases D
  unsigned short* v = (unsigned short*)D + (size_t)NP * 256;

  cvtw_kernel<<<dim3(2, 2),   256, 0, stream>>>(W1b, wbt1, 64, 64);
  cvtw_kernel<<<dim3(2, 2),   256, 0, stream>>>(W2b, wbt2, 64, 64);
  cvtw_kernel<<<dim3(4, 4),   256, 0, stream>>>(W3b, wbt3, 128, 128);
  cvtw_kernel<<<dim3(8, 8),   256, 0, stream>>>(W4b, wbt4, 256, 256);

  dim3 pd_grid(16, 16, 16);
  // layer 1: in pos (C=3) -> xcat[:,0:64]
  sqnorm_kernel<<<NP / 256, 256, 0, stream>>>(pos, 3, 0, 3, sq);
  pairdist_kernel<<<pd_grid, 256, 0, stream>>>(pos, 3, 0, 3, sq, D);
  topk_kernel<<<NP / 4, 256, 0, stream>>>(D, idx);
  transform_kernel<<<dim3(NP / 16, 1), 256, 0, stream>>>(pos, 3, 0, 3, 64, W1a, b1a, u, v);
  edge_mlp_kernel<64, 64, 64><<<2048, 320, 0, stream>>>(u, v, idx, wbt1, b1b, xcat, 0);
  // layer 2: in xcat[:,0:64] -> xcat[:,64:128]
  sqnorm_kernel<<<NP / 256, 256, 0, stream>>>(xcat, 512, 0, 64, sq);
  pairdist_kernel<<<pd_grid, 256, 0, stream>>>(xcat, 512, 0, 64, sq, D);
  topk_kernel<<<NP / 4, 256, 0, stream>>>(D, idx);
  transform_kernel<<<dim3(NP / 16, 1), 256, 0, stream>>>(xcat, 512, 0, 64, 64, W2a, b2a, u, v);
  edge_mlp_kernel<64, 64, 64><<<2048, 320, 0, stream>>>(u, v, idx, wbt2, b2b, xcat, 64);
  // layer 3: in xcat[:,64:128] -> xcat[:,128:256]
  sqnorm_kernel<<<NP / 256, 256, 0, stream>>>(xcat, 512, 64, 64, sq);
  pairdist_kernel<<<pd_grid, 256, 0, stream>>>(xcat, 512, 64, 64, sq, D);
  topk_kernel<<<NP / 4, 256, 0, stream>>>(D, idx);
  transform_kernel<<<dim3(NP / 16, 2), 256, 0, stream>>>(xcat, 512, 64, 64, 128, W3a, b3a, u, v);
  edge_mlp_kernel<128, 128, 32><<<2048, 320, 0, stream>>>(u, v, idx, wbt3, b3b, xcat, 128);
  // layer 4: in xcat[:,128:256] -> xcat[:,256:512]
  sqnorm_kernel<<<NP / 256, 256, 0, stream>>>(xcat, 512, 128, 128, sq);
  pairdist_kernel<<<pd_grid, 256, 0, stream>>>(xcat, 512, 128, 128, sq, D);
  topk_kernel<<<NP / 4, 256, 0, stream>>>(D, idx);
  transform_kernel<<<dim3(NP / 16, 4), 256, 0, stream>>>(xcat, 512, 128, 128, 256, W4a, b4a, u, v);
  edge_mlp_kernel<256, 256, 32><<<2048, 320, 0, stream>>>(u, v, idx, wbt4, b4b, xcat, 256);
  // head
  pool1_kernel<<<dim3(16, 8), 256, 0, stream>>>(xcat, part);
  pool2_kernel<<<16, 256, 0, stream>>>(part, pooled);
  lin1_kernel<<<64, 256, 0, stream>>>(pooled, lin1_w, lin1_b, h);
  bn_kernel<<<4, 256, 0, stream>>>(h, gamma, beta, h2);
  lin2_kernel<<<16, 64, 0, stream>>>(h2, lin2_w, lin2_b, out);
}

// Round 7
// 747.013 us; speedup vs baseline: 1.2066x; 1.2066x over previous
//
#include <hip/hip_runtime.h>
#include <hip/hip_bf16.h>

#define B_   16
#define N_   1024
#define KNN  20
#define NP   (B_ * N_)   // 16384

typedef short bf16x8 __attribute__((ext_vector_type(8)));
typedef float f32x4  __attribute__((ext_vector_type(4)));
typedef float f32x16 __attribute__((ext_vector_type(16)));

__device__ __forceinline__ unsigned short f2bf(float f) {
  unsigned u = __float_as_uint(f);
  u += 0x7fffu + ((u >> 16) & 1u);   // RNE
  return (unsigned short)(u >> 16);
}

// ---------------------------------------------------------------------------
// Row squared norms: sq[p] = sum_c X[p][c]^2  (fp32)
// ---------------------------------------------------------------------------
__global__ __launch_bounds__(256) void sqnorm_kernel(
    const float* __restrict__ X, int LD, int coff, int C, float* __restrict__ sq) {
  int p = blockIdx.x * 256 + threadIdx.x;
  const float* row = X + (size_t)p * LD + coff;
  float s = 0.f;
  if ((C & 3) == 0) {
    for (int c = 0; c < C; c += 4) {
      float4 vv = *(const float4*)(row + c);
      s = fmaf(vv.x, vv.x, s); s = fmaf(vv.y, vv.y, s);
      s = fmaf(vv.z, vv.z, s); s = fmaf(vv.w, vv.w, s);
    }
  } else {
    for (int c = 0; c < C; ++c) { float vv = row[c]; s = fmaf(vv, vv, s); }
  }
  sq[p] = s;
}

// ---------------------------------------------------------------------------
// Pairwise squared distances, Gram form, emitted as PACKED u32 SORT KEYS:
//   key[i][j] = (float_bits(max(d,0)) & 0xFFFFFC00) | j
// Float bits are order-monotone for d>=0 (clamp handles Gram-form negative
// rounding, which would otherwise sort last in unsigned compare). Dropping
// 10 mantissa bits (rel 1.2e-4) only reorders feature-space near-duplicates;
// exact ties break to lowest j, matching jax.lax.top_k. Halves D traffic.
// ---------------------------------------------------------------------------
__global__ __launch_bounds__(256) void pairdist_kernel(
    const float* __restrict__ X, int LD, int coff, int C,
    const float* __restrict__ sq, unsigned* __restrict__ Dk) {
  __shared__ float Xi[16][68];
  __shared__ float Xj[16][68];
  int b  = blockIdx.z;
  int i0 = blockIdx.y * 64, j0 = blockIdx.x * 64;
  int t  = threadIdx.x;
  int tx = t & 15, ty = t >> 4;
  float acc[4][4] = {};
  for (int c0 = 0; c0 < C; c0 += 16) {
    int cc = min(16, C - c0);
    if (tx < cc) {
      for (int r = ty; r < 64; r += 16) {
        Xi[tx][r] = X[(size_t)(b * N_ + i0 + r) * LD + coff + c0 + tx];
        Xj[tx][r] = X[(size_t)(b * N_ + j0 + r) * LD + coff + c0 + tx];
      }
    }
    __syncthreads();
    for (int c = 0; c < cc; ++c) {
      float4 a4 = *(const float4*)&Xi[c][ty * 4];
      float4 b4 = *(const float4*)&Xj[c][tx * 4];
      float a[4] = {a4.x, a4.y, a4.z, a4.w};
      float bb[4] = {b4.x, b4.y, b4.z, b4.w};
#pragma unroll
      for (int p = 0; p < 4; ++p)
#pragma unroll
        for (int q = 0; q < 4; ++q)
          acc[p][q] = fmaf(a[p], bb[q], acc[p][q]);
    }
    __syncthreads();
  }
  float sqi[4], sqj[4];
#pragma unroll
  for (int p = 0; p < 4; ++p) sqi[p] = sq[b * N_ + i0 + ty * 4 + p];
#pragma unroll
  for (int q = 0; q < 4; ++q) sqj[q] = sq[b * N_ + j0 + tx * 4 + q];
#pragma unroll
  for (int p = 0; p < 4; ++p) {
    uint4 st;
    unsigned* kk = (unsigned*)&st;
#pragma unroll
    for (int q = 0; q < 4; ++q) {
      float d = fmaxf((sqi[p] - 2.f * acc[p][q]) + sqj[q], 0.f);
      kk[q] = (__float_as_uint(d) & 0xFFFFFC00u) | (unsigned)(j0 + tx * 4 + q);
    }
    *(uint4*)&Dk[(size_t)(b * N_ + i0 + ty * 4 + p) * N_ + j0 + tx * 4] = st;
  }
}

// ---------------------------------------------------------------------------
// Top-K=20 smallest keys per point. One wave per point; keys are u32
// (dist_bits | j) so min-extraction is v_min_u32 + 32-bit shuffles.
// ---------------------------------------------------------------------------
__global__ __launch_bounds__(256) void topk_kernel(
    const unsigned* __restrict__ Dk, int* __restrict__ idx) {
  int w = threadIdx.x >> 6, lane = threadIdx.x & 63;
  int p = blockIdx.x * 4 + w;
  const unsigned* row = Dk + (size_t)p * N_;
  unsigned key[16];
#pragma unroll
  for (int s = 0; s < 16; ++s) key[s] = row[lane + 64 * s];
  int base = p & ~(N_ - 1);
  for (int k = 0; k < KNN; ++k) {
    unsigned m = key[0];
#pragma unroll
    for (int s = 1; s < 16; ++s) m = min(m, key[s]);
#pragma unroll
    for (int off = 32; off >= 1; off >>= 1)
      m = min(m, (unsigned)__shfl_xor((int)m, off));
    int j = (int)(m & 1023u);
    if (lane == 0) idx[p * KNN + k] = base + j;
    if ((j & 63) == lane) key[j >> 6] = 0xFFFFFFFFu;
  }
}

// ---------------------------------------------------------------------------
// Per-point transform: u = x@(Wa_top - Wa_bot) + ba ; v = x@Wa_bot
// fp32 accumulate, bf16 out. X rows staged in LDS.
// ---------------------------------------------------------------------------
__global__ __launch_bounds__(256) void transform_kernel(
    const float* __restrict__ X, int LD, int coff, int Cin, int Cmid,
    const float* __restrict__ Wa, const float* __restrict__ ba,
    unsigned short* __restrict__ u, unsigned short* __restrict__ v) {
  __shared__ float xs[16 * 128];
  int w = threadIdx.x >> 6, lane = threadIdx.x & 63;
  int m  = blockIdx.y * 64 + lane;
  int p0 = blockIdx.x * 16;
  if ((Cin & 3) == 0) {
    for (int i = threadIdx.x; i < 16 * (Cin / 4); i += 256) {
      int pt = i / (Cin / 4), q = i - pt * (Cin / 4);
      *(float4*)&xs[pt * Cin + q * 4] =
          *(const float4*)&X[(size_t)(p0 + pt) * LD + coff + q * 4];
    }
  } else {
    for (int i = threadIdx.x; i < 16 * Cin; i += 256) {
      int pt = i / Cin, c = i - pt * Cin;
      xs[pt * Cin + c] = X[(size_t)(p0 + pt) * LD + coff + c];
    }
  }
  __syncthreads();
  const float* xw = xs + (w * 4) * Cin;
  float ua[4] = {0.f, 0.f, 0.f, 0.f}, va[4] = {0.f, 0.f, 0.f, 0.f};
  for (int c = 0; c < Cin; ++c) {
    float wt = Wa[(size_t)c * Cmid + m];
    float wb = Wa[(size_t)(Cin + c) * Cmid + m];
    float wd = wt - wb;
#pragma unroll
    for (int i = 0; i < 4; ++i) {
      float xv = xw[i * Cin + c];
      ua[i] = fmaf(xv, wd, ua[i]);
      va[i] = fmaf(xv, wb, va[i]);
    }
  }
  float bias = ba[m];
#pragma unroll
  for (int i = 0; i < 4; ++i) {
    u[(size_t)(p0 + w * 4 + i) * Cmid + m] = f2bf(ua[i] + bias);
    v[(size_t)(p0 + w * 4 + i) * Cmid + m] = f2bf(va[i]);
  }
}

// ---------------------------------------------------------------------------
// Batched transpose+convert of all four Wb (Cmid x Cout, fp32) -> bf16 WbT.
// grid.z selects layer; out-of-range 32x32 tiles early-out.
// ---------------------------------------------------------------------------
__global__ __launch_bounds__(256) void cvtw4_kernel(
    const float* __restrict__ W0, const float* __restrict__ W1,
    const float* __restrict__ W2, const float* __restrict__ W3,
    unsigned short* __restrict__ o0, unsigned short* __restrict__ o1,
    unsigned short* __restrict__ o2, unsigned short* __restrict__ o3) {
  __shared__ unsigned short tile[32][33];
  int z = blockIdx.z;
  const float* W; unsigned short* out; int Cmid, Cout;
  if (z == 0)      { W = W0; out = o0; Cmid = 64;  Cout = 64;  }
  else if (z == 1) { W = W1; out = o1; Cmid = 64;  Cout = 64;  }
  else if (z == 2) { W = W2; out = o2; Cmid = 128; Cout = 128; }
  else             { W = W3; out = o3; Cmid = 256; Cout = 256; }
  int c0 = blockIdx.x * 32, co0 = blockIdx.y * 32;
  if (c0 >= Cmid || co0 >= Cout) return;
  int tx = threadIdx.x & 31, ty = threadIdx.x >> 5;   // 32 x 8
  for (int r = ty; r < 32; r += 8)
    tile[r][tx] = f2bf(W[(size_t)(c0 + r) * Cout + co0 + tx]);
  __syncthreads();
  for (int r = ty; r < 32; r += 8)
    out[(size_t)(co0 + r) * Cmid + c0 + tx] = tile[tx][r];
}

// ---------------------------------------------------------------------------
// Edge MLP second GEMM + max-aggregate (round-5 proven version).
// mfma_f32_32x32x16_bf16; block: 320 threads (5 waves) = 160 edges = 8 points.
// A-frags (relu(u_p+v_j) bf16) built in regs from global, cached across groups.
// ---------------------------------------------------------------------------
template<int Cmid, int Cout, int CG>
__global__ __launch_bounds__(320, 4) void edge_mlp_kernel(
    const unsigned short* __restrict__ u, const unsigned short* __restrict__ v,
    const int* __restrict__ idx,
    const unsigned short* __restrict__ wbt, const float* __restrict__ bb,
    float* __restrict__ xcat, int coff) {
  constexpr int AP = Cmid + 8;
  constexpr int T  = CG / 32;      // 32-col tiles per group
  constexpr int KC = Cmid / 16;    // k chunks of 16
  constexpr int G  = Cout / CG;    // col groups
  __shared__ __align__(16) unsigned short W_lds[CG * AP];
  __shared__ float qmax[40 * CG];
  int tid = threadIdx.x, w = tid >> 6, lane = tid & 63;
  int col = lane & 31, half = lane >> 5;

  int rg = blockIdx.x * 160 + w * 32 + col;
  int p  = rg / 20;
  int j  = idx[rg];
  const unsigned short* up = u + (size_t)p * Cmid + half * 8;
  const unsigned short* vp = v + (size_t)j * Cmid + half * 8;

  bf16x8 afr[KC];
#pragma unroll
  for (int c = 0; c < KC; ++c) {
    union { int4 i; __hip_bfloat162 h[4]; bf16x8 vec; } U, V, R;
    U.i = *(const int4*)(up + c * 16);
    V.i = *(const int4*)(vp + c * 16);
#pragma unroll
    for (int q = 0; q < 4; ++q) {
      float2 a = __bfloat1622float2(U.h[q]);
      float2 b = __bfloat1622float2(V.h[q]);
      R.h[q] = __float22bfloat162_rn({fmaxf(a.x + b.x, 0.f), fmaxf(a.y + b.y, 0.f)});
    }
    afr[c] = R.vec;
  }

  int brow = col * AP + half * 8;

  for (int g = 0; g < G; ++g) {
    __syncthreads();
    for (int i = tid; i < CG * (Cmid / 8); i += 320) {
      int rr = i / (Cmid / 8), q = i - rr * (Cmid / 8);
      *(int4*)&W_lds[rr * AP + q * 8] =
          *(const int4*)&wbt[(size_t)(g * CG + rr) * Cmid + q * 8];
    }
    __syncthreads();
    f32x16 acc[T] = {};
#pragma unroll
    for (int c = 0; c < KC; ++c) {
#pragma unroll
      for (int t = 0; t < T; ++t) {
        bf16x8 bf = *(const bf16x8*)&W_lds[brow + t * 32 * AP + c * 16];
        acc[t] = __builtin_amdgcn_mfma_f32_32x32x16_bf16(afr[c], bf, acc[t], 0, 0, 0);
      }
    }
#pragma unroll
    for (int t = 0; t < T; ++t) {
#pragma unroll
      for (int Q = 0; Q < 4; ++Q) {
        float m0 = fmaxf(fmaxf(acc[t][4 * Q], acc[t][4 * Q + 1]),
                         fmaxf(acc[t][4 * Q + 2], acc[t][4 * Q + 3]));
        qmax[(w * 8 + 2 * Q + half) * CG + t * 32 + col] = m0;
      }
    }
    __syncthreads();
    for (int i = tid; i < 8 * CG; i += 320) {
      int pl = i / CG, c2 = i - pl * CG;
      float mm = qmax[(pl * 5 + 0) * CG + c2];
#pragma unroll
      for (int qq = 1; qq < 5; ++qq) mm = fmaxf(mm, qmax[(pl * 5 + qq) * CG + c2]);
      int pg = blockIdx.x * 8 + pl;
      xcat[(size_t)pg * 512 + coff + g * CG + c2] = mm + bb[g * CG + c2];
    }
  }
}

// ---------------------------------------------------------------------------
// Global max pool, two-stage coalesced.
// ---------------------------------------------------------------------------
__global__ __launch_bounds__(256) void pool1_kernel(const float* __restrict__ xcat,
                                                    float* __restrict__ part) {
  int b = blockIdx.x, g = blockIdx.y, t = threadIdx.x;
  const float* base = xcat + ((size_t)b * N_ + g * 128) * 512 + t * 2;
  float mx = -__builtin_inff(), my = -__builtin_inff();
#pragma unroll 4
  for (int r = 0; r < 128; ++r) {
    float2 vv = *(const float2*)(base + (size_t)r * 512);
    mx = fmaxf(mx, vv.x);
    my = fmaxf(my, vv.y);
  }
  *(float2*)&part[((size_t)b * 8 + g) * 512 + t * 2] = make_float2(mx, my);
}

__global__ __launch_bounds__(256) void pool2_kernel(const float* __restrict__ part,
                                                    float* __restrict__ pooled) {
  int b = blockIdx.x, t = threadIdx.x;
  float2 m = *(const float2*)&part[(size_t)b * 8 * 512 + t * 2];
#pragma unroll
  for (int g = 1; g < 8; ++g) {
    float2 vv = *(const float2*)&part[((size_t)b * 8 + g) * 512 + t * 2];
    m.x = fmaxf(m.x, vv.x);
    m.y = fmaxf(m.y, vv.y);
  }
  *(float2*)&pooled[b * 512 + t * 2] = m;
}

__global__ __launch_bounds__(256) void lin1_kernel(const float* __restrict__ pooled,
                                                   const float* __restrict__ W,
                                                   const float* __restrict__ bias,
                                                   float* __restrict__ h) {
  int flat = blockIdx.x * 256 + threadIdx.x;
  int b = flat >> 10, m = flat & 1023;
  float s = 0.f;
  for (int c = 0; c < 512; ++c) s = fmaf(pooled[b * 512 + c], W[(size_t)c * 1024 + m], s);
  h[flat] = s + bias[m];
}

__global__ __launch_bounds__(256) void bn_kernel(const float* __restrict__ h,
                                                 const float* __restrict__ gamma,
                                                 const float* __restrict__ beta,
                                                 float* __restrict__ h2) {
  int m = blockIdx.x * 256 + threadIdx.x;
  float s = 0.f;
  for (int b = 0; b < 16; ++b) s += h[b * 1024 + m];
  float mu = s * (1.f / 16.f);
  float vv = 0.f;
  for (int b = 0; b < 16; ++b) { float d = h[b * 1024 + m] - mu; vv = fmaf(d, d, vv); }
  vv *= (1.f / 16.f);
  float rstd = rsqrtf(vv + 1e-5f);
  float g = gamma[m] * rstd, be = beta[m];
  for (int b = 0; b < 16; ++b) {
    float val = (h[b * 1024 + m] - mu) * g + be;
    h2[b * 1024 + m] = fmaxf(val, 0.f);
  }
}

__global__ __launch_bounds__(64) void lin2_kernel(const float* __restrict__ h2,
                                                  const float* __restrict__ W,
                                                  const float* __restrict__ bias,
                                                  float* __restrict__ out) {
  int b = blockIdx.x, lane = threadIdx.x;
  float logit = 0.f;
  if (lane < 40) {
    logit = bias[lane];
    for (int c = 0; c < 1024; ++c)
      logit = fmaf(h2[b * 1024 + c], W[(size_t)c * 40 + lane], logit);
  }
  float mv = (lane < 40) ? logit : -__builtin_inff();
#pragma unroll
  for (int off = 32; off >= 1; off >>= 1) mv = fmaxf(mv, __shfl_xor(mv, off));
  float e = (lane < 40) ? expf(logit - mv) : 0.f;
#pragma unroll
  for (int off = 32; off >= 1; off >>= 1) e += __shfl_xor(e, off);
  float lse = mv + logf(e);
  if (lane < 40) out[b * 40 + lane] = logit - lse;
}

// ---------------------------------------------------------------------------
extern "C" void kernel_launch(void* const* d_in, const int* in_sizes, int n_in,
                              void* d_out, int out_size, void* d_ws, size_t ws_size,
                              hipStream_t stream) {
  const float* pos    = (const float*)d_in[0];
  const float* W1a = (const float*)d_in[2];  const float* b1a = (const float*)d_in[3];
  const float* W1b = (const float*)d_in[4];  const float* b1b = (const float*)d_in[5];
  const float* W2a = (const float*)d_in[6];  const float* b2a = (const float*)d_in[7];
  const float* W2b = (const float*)d_in[8];  const float* b2b = (const float*)d_in[9];
  const float* W3a = (const float*)d_in[10]; const float* b3a = (const float*)d_in[11];
  const float* W3b = (const float*)d_in[12]; const float* b3b = (const float*)d_in[13];
  const float* W4a = (const float*)d_in[14]; const float* b4a = (const float*)d_in[15];
  const float* W4b = (const float*)d_in[16]; const float* b4b = (const float*)d_in[17];
  const float* lin1_w = (const float*)d_in[18]; const float* lin1_b = (const float*)d_in[19];
  const float* gamma  = (const float*)d_in[20]; const float* beta   = (const float*)d_in[21];
  const float* lin2_w = (const float*)d_in[22]; const float* lin2_b = (const float*)d_in[23];
  float* out = (float*)d_out;

  char* ws = (char*)d_ws;
  size_t off = 0;
  auto alloc = [&](size_t bytes) {
    void* p = ws + off; off += (bytes + 255) & ~(size_t)255; return p;
  };
  float*    xcat = (float*)alloc((size_t)NP * 512 * 4);   // 32 MB
  unsigned* Dk   = (unsigned*)alloc((size_t)NP * N_ * 4); // 64 MB (u/v alias inside)
  int*      idx  = (int*)alloc((size_t)NP * KNN * 4);
  float*    sq   = (float*)alloc((size_t)NP * 4);
  unsigned short* wbt1 = (unsigned short*)alloc(64 * 64 * 2);
  unsigned short* wbt2 = (unsigned short*)alloc(64 * 64 * 2);
  unsigned short* wbt3 = (unsigned short*)alloc(128 * 128 * 2);
  unsigned short* wbt4 = (unsigned short*)alloc(256 * 256 * 2);
  float* h      = (float*)alloc(16 * 1024 * 4);
  float* h2     = (float*)alloc(16 * 1024 * 4);
  float* pooled = (float*)alloc(16 * 512 * 4);
  float* part   = (float*)alloc(16 * 8 * 512 * 4);
  unsigned short* u = (unsigned short*)Dk;             // bf16, aliases Dk
  unsigned short* v = (unsigned short*)Dk + (size_t)NP * 256;

  cvtw4_kernel<<<dim3(8, 8, 4), 256, 0, stream>>>(W1b, W2b, W3b, W4b,
                                                  wbt1, wbt2, wbt3, wbt4);

  dim3 pd_grid(16, 16, 16);
  // layer 1: in pos (C=3) -> xcat[:,0:64]
  sqnorm_kernel<<<NP / 256, 256, 0, stream>>>(pos, 3, 0, 3, sq);
  pairdist_kernel<<<pd_grid, 256, 0, stream>>>(pos, 3, 0, 3, sq, Dk);
  topk_kernel<<<NP / 4, 256, 0, stream>>>(Dk, idx);
  transform_kernel<<<dim3(NP / 16, 1), 256, 0, stream>>>(pos, 3, 0, 3, 64, W1a, b1a, u, v);
  edge_mlp_kernel<64, 64, 64><<<2048, 320, 0, stream>>>(u, v, idx, wbt1, b1b, xcat, 0);
  // layer 2: in xcat[:,0:64] -> xcat[:,64:128]
  sqnorm_kernel<<<NP / 256, 256, 0, stream>>>(xcat, 512, 0, 64, sq);
  pairdist_kernel<<<pd_grid, 256, 0, stream>>>(xcat, 512, 0, 64, sq, Dk);
  topk_kernel<<<NP / 4, 256, 0, stream>>>(Dk, idx);
  transform_kernel<<<dim3(NP / 16, 1), 256, 0, stream>>>(xcat, 512, 0, 64, 64, W2a, b2a, u, v);
  edge_mlp_kernel<64, 64, 64><<<2048, 320, 0, stream>>>(u, v, idx, wbt2, b2b, xcat, 64);
  // layer 3: in xcat[:,64:128] -> xcat[:,128:256]
  sqnorm_kernel<<<NP / 256, 256, 0, stream>>>(xcat, 512, 64, 64, sq);
  pairdist_kernel<<<pd_grid, 256, 0, stream>>>(xcat, 512, 64, 64, sq, Dk);
  topk_kernel<<<NP / 4, 256, 0, stream>>>(Dk, idx);
  transform_kernel<<<dim3(NP / 16, 2), 256, 0, stream>>>(xcat, 512, 64, 64, 128, W3a, b3a, u, v);
  edge_mlp_kernel<128, 128, 64><<<2048, 320, 0, stream>>>(u, v, idx, wbt3, b3b, xcat, 128);
  // layer 4: in xcat[:,128:256] -> xcat[:,256:512]
  sqnorm_kernel<<<NP / 256, 256, 0, stream>>>(xcat, 512, 128, 128, sq);
  pairdist_kernel<<<pd_grid, 256, 0, stream>>>(xcat, 512, 128, 128, sq, Dk);
  topk_kernel<<<NP / 4, 256, 0, stream>>>(Dk, idx);
  transform_kernel<<<dim3(NP / 16, 4), 256, 0, stream>>>(xcat, 512, 128, 128, 256, W4a, b4a, u, v);
  edge_mlp_kernel<256, 256, 32><<<2048, 320, 0, stream>>>(u, v, idx, wbt4, b4b, xcat, 256);
  // head
  pool1_kernel<<<dim3(16, 8), 256, 0, stream>>>(xcat, part);
  pool2_kernel<<<16, 256, 0, stream>>>(part, pooled);
  lin1_kernel<<<64, 256, 0, stream>>>(pooled, lin1_w, lin1_b, h);
  bn_kernel<<<4, 256, 0, stream>>>(h, gamma, beta, h2);
  lin2_kernel<<<16, 64, 0, stream>>>(h2, lin2_w, lin2_b, out);
}